// Round 1
// baseline (813.304 us; speedup 1.0000x reference)
//
#include <hip/hip_runtime.h>
#include <hip/hip_cooperative_groups.h>

namespace cg = cooperative_groups;

#define NN 768
#define IN_F 68
#define KNN 8
#define EO 32
#define FEAT 264
#define HALF_FEAT 132
#define EMB 32
#define NPAIR 294528   // 768*767/2

typedef __attribute__((ext_vector_type(8))) short bf16x8;
typedef __attribute__((ext_vector_type(4))) float f32x4;

// pack hi16(x1):hi16(x0) into one dword — bf16 truncation of two floats, 1 v_perm
static __device__ __forceinline__ int pack_chop2(float x0, float x1) {
  return __builtin_amdgcn_perm(__float_as_uint(x1), __float_as_uint(x0), 0x07060302);
}
static __device__ __forceinline__ float chop(float x) {
  return __uint_as_float(__float_as_uint(x) & 0xffff0000u);
}

// =====================================================================
// Fused cooperative kernel: phases A (topk+ec1) / B (ec2) / C (BN stats)
// / D (per-node u,v + c0), separated by grid-wide barriers.
// Grid (769,2) x 64 threads = 1538 one-wave blocks; ~7KB LDS -> ~20
// blocks/CU capacity, 6.01 needed -> co-resident, coop launch valid.
// =====================================================================
__global__ void __launch_bounds__(64) fused_abcd_kernel(
    const float* __restrict__ feat0, const float* __restrict__ feat1,
    const float* __restrict__ ec1_w1, const float* __restrict__ ec1_b1,
    const float* __restrict__ ec1_w2, const float* __restrict__ ec1_b2,
    const float* __restrict__ ec2_w1, const float* __restrict__ ec2_b1,
    const float* __restrict__ ec2_w2, const float* __restrict__ ec2_b2,
    const float* __restrict__ bn_g, const float* __restrict__ bn_b,
    const float* __restrict__ lin1_w, const float* __restrict__ lin1_b,
    int* idx, float* e1, float* e2,
    float* mu, float* sg,
    float* u, float* v, float* c0g)
{
  cg::grid_group grid = cg::this_grid();
  const int i = blockIdx.x;     // 0..768
  const int g = blockIdx.y;     // 0..1
  const int lane = threadIdx.x;

  __shared__ unsigned long long keys[64*8];
  __shared__ int nbr[8];
  __shared__ float gl[KNN*IN_F];   // phase A: 8x68; phase B reuses as 8x32
  __shared__ float hsh[EO];
  __shared__ float xsh[HALF_FEAT];

  // ---------------- phase A: top-8 neighbors + EdgeConv1 ----------------
  if (i < NN) {
    const float* __restrict__ feat = g ? feat1 : feat0;
    const float4 ci = *(const float4*)(feat + i*IN_F);

    float4 cand[12];
#pragma unroll
    for (int t = 0; t < 12; t++)
      cand[t] = *(const float4*)(feat + (lane + 64*t)*IN_F);

    float bd[8]; int bidx[8];
#pragma unroll
    for (int k = 0; k < 8; k++) { bd[k] = 1e30f; bidx[k] = 0; }
#pragma unroll
    for (int t = 0; t < 12; t++) {
      const int j = lane + 64*t;
      float d = fabsf(ci.x - cand[t].x);   // same sequential add order as ref sum(-1)
      d += fabsf(ci.y - cand[t].y);
      d += fabsf(ci.z - cand[t].z);
      d += fabsf(ci.w - cand[t].w);
      if (d < bd[7]) {
#pragma unroll
        for (int k = 7; k >= 1; k--) {
          if (d < bd[k-1])    { bd[k] = bd[k-1]; bidx[k] = bidx[k-1]; }
          else if (d < bd[k]) { bd[k] = d;       bidx[k] = j; }
        }
        if (d < bd[0]) { bd[0] = d; bidx[0] = j; }
      }
    }
#pragma unroll
    for (int k = 0; k < 8; k++)
      keys[lane*8+k] = ((unsigned long long)__float_as_uint(bd[k]) << 32) | (unsigned)bidx[k];
    __syncthreads();
    int pos = 0;
#pragma unroll
    for (int r = 0; r < 8; r++) {
      unsigned long long mykey = keys[lane*8 + pos];
      unsigned long long mn = mykey;
#pragma unroll
      for (int s = 32; s >= 1; s >>= 1) {
        unsigned long long o = __shfl_xor(mn, s, 64);
        mn = (o < mn) ? o : mn;
      }
      if (mykey == mn) pos++;
      if (lane == 0) {
        int nb = (int)(mn & 0xffffffffull);
        nbr[r] = nb;
        idx[(g*NN+i)*8 + r] = nb;
      }
    }
    __syncthreads();

    for (int z = lane; z < KNN*17; z += 64) {
      int k = z / 17, q = z - k*17;
      *(float4*)&gl[k*IN_F + q*4] = *(const float4*)(feat + nbr[k]*IN_F + q*4);
    }
    __syncthreads();

    // layer1, 8 independent accumulator chains (k-major) for ILP
    const int e = lane & 31, hf = lane >> 5;
    float ak[8];
#pragma unroll
    for (int k = 0; k < 8; k++) ak[k] = 0.f;
    const int cbeg = hf*34;
    for (int c = cbeg; c < cbeg+34; c++) {
#pragma unroll
      for (int k = 0; k < 8; k++)
        ak[k] += gl[k*IN_F+c] * ec1_w1[(c*8+k)*EO + e];
    }
    float acc = ((ak[0]+ak[1])+(ak[2]+ak[3])) + ((ak[4]+ak[5])+(ak[6]+ak[7]));
    acc += __shfl_xor(acc, 32, 64);
    if (hf == 0) {
      float h = acc + ec1_b1[e];
      hsh[e] = fmaxf(h, 0.01f*h);
    }
    __syncthreads();
    if (lane < 32) {
      float o0=0.f, o1=0.f, o2=0.f, o3=0.f;
#pragma unroll
      for (int m = 0; m < 32; m += 4) {
        o0 += hsh[m+0] * ec1_w2[(m+0)*EO + lane];
        o1 += hsh[m+1] * ec1_w2[(m+1)*EO + lane];
        o2 += hsh[m+2] * ec1_w2[(m+2)*EO + lane];
        o3 += hsh[m+3] * ec1_w2[(m+3)*EO + lane];
      }
      float o = ec1_b2[lane] + ((o0+o1)+(o2+o3));
      o = fmaxf(o, 0.01f*o);
      e1[(g*NN+i)*EO + lane] = o;
    }
  }
  __threadfence();
  grid.sync();

  // ---------------- phase B: EdgeConv2 ----------------
  if (i < NN) {
    {
      const int k = lane >> 3, q = lane & 7;
      const int nb = idx[(g*NN+i)*8 + k];
      *(float4*)&gl[k*EO + q*4] = *(const float4*)(e1 + (g*NN+nb)*EO + q*4);
    }
    __syncthreads();
    const int e = lane & 31, hf = lane >> 5;
    float ak[8];
#pragma unroll
    for (int k = 0; k < 8; k++) ak[k] = 0.f;
    const int cbeg = hf*16;
    for (int c = cbeg; c < cbeg+16; c++) {
#pragma unroll
      for (int k = 0; k < 8; k++)
        ak[k] += gl[k*EO+c] * ec2_w1[(c*8+k)*EO + e];
    }
    float acc = ((ak[0]+ak[1])+(ak[2]+ak[3])) + ((ak[4]+ak[5])+(ak[6]+ak[7]));
    acc += __shfl_xor(acc, 32, 64);
    if (hf == 0) {
      float h = acc + ec2_b1[e];
      hsh[e] = fmaxf(h, 0.01f*h);
    }
    __syncthreads();
    if (lane < 32) {
      float o0=0.f, o1=0.f, o2=0.f, o3=0.f;
#pragma unroll
      for (int m = 0; m < 32; m += 4) {
        o0 += hsh[m+0] * ec2_w2[(m+0)*EO + lane];
        o1 += hsh[m+1] * ec2_w2[(m+1)*EO + lane];
        o2 += hsh[m+2] * ec2_w2[(m+2)*EO + lane];
        o3 += hsh[m+3] * ec2_w2[(m+3)*EO + lane];
      }
      float o = ec2_b2[lane] + ((o0+o1)+(o2+o3));
      o = fmaxf(o, 0.01f*o);
      e2[(g*NN+i)*EO + lane] = o;
    }
  }
  __threadfence();
  grid.sync();

  // ---------------- phase C: BN stats (132 one-wave channel blocks) ----------------
  if (g == 0 && i < HALF_FEAT) {
    const int c = i;
    double s1=0, s2=0, q1=0, q2=0;
    for (int t = lane; t < 2*NN; t += 64) {
      int gg = t >= NN;
      int n = t - gg*NN;
      float val;
      if (c < IN_F)      val = (gg ? feat1 : feat0)[n*IN_F + c];
      else if (c < 100)  val = e1[(gg*NN+n)*EO + (c-IN_F)];
      else               val = e2[(gg*NN+n)*EO + (c-100)];
      double dv = val;
      double wf = (double)(NN-1-n), wsnd = (double)n;
      s1 += wf*dv;  s2 += wsnd*dv;
      double dq = dv*dv;
      q1 += wf*dq;  q2 += wsnd*dq;
    }
#pragma unroll
    for (int off = 32; off >= 1; off >>= 1) {
      s1 += __shfl_xor(s1, off, 64);
      s2 += __shfl_xor(s2, off, 64);
      q1 += __shfl_xor(q1, off, 64);
      q2 += __shfl_xor(q2, off, 64);
    }
    if (lane == 0) {
      const double M2 = 2.0 * (double)NPAIR;
      double mu1 = s1/M2, mu2 = s2/M2;
      double v1 = q1/M2 - mu1*mu1;
      double v2 = q2/M2 - mu2*mu2;
      mu[c]           = (float)mu1;
      mu[HALF_FEAT+c] = (float)mu2;
      sg[c]           = (float)((double)bn_g[c] / sqrt(v1 + 1e-5));
      sg[HALF_FEAT+c] = (float)((double)bn_g[HALF_FEAT+c] / sqrt(v2 + 1e-5));
    }
  }
  __threadfence();
  grid.sync();

  // ---------------- phase D: per-node u/v, plus c0 ----------------
  if (i == NN) {
    if (g == 0 && lane < EMB) {
      float a0=0.f, a1=0.f, a2=0.f, a3=0.f;
      for (int c = 0; c < FEAT; c += 4) {
        a0 += (bn_b[c+0] - mu[c+0]*sg[c+0]) * lin1_w[(c+0)*EMB + lane];
        a1 += (bn_b[c+1] - mu[c+1]*sg[c+1]) * lin1_w[(c+1)*EMB + lane];
        a2 += (bn_b[c+2] - mu[c+2]*sg[c+2]) * lin1_w[(c+2)*EMB + lane];
        a3 += (bn_b[c+3] - mu[c+3]*sg[c+3]) * lin1_w[(c+3)*EMB + lane];
      }
      c0g[lane] = lin1_b[lane] + ((a0+a1)+(a2+a3));
    }
  } else {
    for (int c = lane; c < IN_F; c += 64) xsh[c] = (g ? feat1 : feat0)[i*IN_F + c];
    if (lane < 32) xsh[IN_F + lane]       = e1[(g*NN+i)*EO + lane];
    else           xsh[100 + (lane-32)]   = e2[(g*NN+i)*EO + (lane-32)];
    __syncthreads();
    const int e = lane & 31, hf = lane >> 5;
    const int base = hf * HALF_FEAT;
    float a0=0.f, a1=0.f, a2=0.f, a3=0.f;
    for (int c = 0; c < HALF_FEAT; c += 4) {
      a0 += xsh[c+0] * sg[base+c+0] * lin1_w[(base+c+0)*EMB + e];
      a1 += xsh[c+1] * sg[base+c+1] * lin1_w[(base+c+1)*EMB + e];
      a2 += xsh[c+2] * sg[base+c+2] * lin1_w[(base+c+2)*EMB + e];
      a3 += xsh[c+3] * sg[base+c+3] * lin1_w[(base+c+3)*EMB + e];
    }
    float acc = ((a0+a1)+(a2+a3));
    float* dst = hf ? v : u;
    dst[(g*NN+i)*EMB + e] = acc;
  }
}

// =====================================================================
// Fallback path (only used if cooperative launch is rejected at enqueue)
// =====================================================================
__global__ void __launch_bounds__(64) topk_ec1_kernel(
    const float* __restrict__ feat0, const float* __restrict__ feat1,
    const float* __restrict__ w1, const float* __restrict__ b1,
    const float* __restrict__ w2, const float* __restrict__ b2,
    int* __restrict__ idx_out, float* __restrict__ e1out)
{
  const int i = blockIdx.x, g = blockIdx.y;
  const float* __restrict__ feat = g ? feat1 : feat0;
  const int lane = threadIdx.x;

  __shared__ unsigned long long keys[64*8];
  __shared__ int nbr[8];
  __shared__ float gl[KNN*IN_F];
  __shared__ float hsh[EO];

  const float4 ci = *(const float4*)(feat + i*IN_F);

  float4 cand[12];
#pragma unroll
  for (int t = 0; t < 12; t++)
    cand[t] = *(const float4*)(feat + (lane + 64*t)*IN_F);

  float bd[8]; int bidx[8];
#pragma unroll
  for (int k = 0; k < 8; k++) { bd[k] = 1e30f; bidx[k] = 0; }
#pragma unroll
  for (int t = 0; t < 12; t++) {
    const int j = lane + 64*t;
    float d = fabsf(ci.x - cand[t].x);
    d += fabsf(ci.y - cand[t].y);
    d += fabsf(ci.z - cand[t].z);
    d += fabsf(ci.w - cand[t].w);
    if (d < bd[7]) {
#pragma unroll
      for (int k = 7; k >= 1; k--) {
        if (d < bd[k-1])    { bd[k] = bd[k-1]; bidx[k] = bidx[k-1]; }
        else if (d < bd[k]) { bd[k] = d;       bidx[k] = j; }
      }
      if (d < bd[0]) { bd[0] = d; bidx[0] = j; }
    }
  }
#pragma unroll
  for (int k = 0; k < 8; k++)
    keys[lane*8+k] = ((unsigned long long)__float_as_uint(bd[k]) << 32) | (unsigned)bidx[k];
  __syncthreads();
  int pos = 0;
#pragma unroll
  for (int r = 0; r < 8; r++) {
    unsigned long long mykey = keys[lane*8 + pos];
    unsigned long long mn = mykey;
#pragma unroll
    for (int s = 32; s >= 1; s >>= 1) {
      unsigned long long o = __shfl_xor(mn, s, 64);
      mn = (o < mn) ? o : mn;
    }
    if (mykey == mn) pos++;
    if (lane == 0) {
      int nb = (int)(mn & 0xffffffffull);
      nbr[r] = nb;
      idx_out[(g*NN+i)*8 + r] = nb;
    }
  }
  __syncthreads();

  for (int z = lane; z < KNN*17; z += 64) {
    int k = z / 17, q = z - k*17;
    *(float4*)&gl[k*IN_F + q*4] = *(const float4*)(feat + nbr[k]*IN_F + q*4);
  }
  __syncthreads();

  const int e = lane & 31, hf = lane >> 5;
  float ak[8];
#pragma unroll
  for (int k = 0; k < 8; k++) ak[k] = 0.f;
  const int cbeg = hf*34;
  for (int c = cbeg; c < cbeg+34; c++) {
#pragma unroll
    for (int k = 0; k < 8; k++)
      ak[k] += gl[k*IN_F+c] * w1[(c*8+k)*EO + e];
  }
  float acc = ((ak[0]+ak[1])+(ak[2]+ak[3])) + ((ak[4]+ak[5])+(ak[6]+ak[7]));
  acc += __shfl_xor(acc, 32, 64);
  if (hf == 0) {
    float h = acc + b1[e];
    hsh[e] = fmaxf(h, 0.01f*h);
  }
  __syncthreads();
  if (lane < 32) {
    float o0=0.f, o1=0.f, o2=0.f, o3=0.f;
#pragma unroll
    for (int m = 0; m < 32; m += 4) {
      o0 += hsh[m+0] * w2[(m+0)*EO + lane];
      o1 += hsh[m+1] * w2[(m+1)*EO + lane];
      o2 += hsh[m+2] * w2[(m+2)*EO + lane];
      o3 += hsh[m+3] * w2[(m+3)*EO + lane];
    }
    float o = b2[lane] + ((o0+o1)+(o2+o3));
    o = fmaxf(o, 0.01f*o);
    e1out[(g*NN+i)*EO + lane] = o;
  }
}

__global__ void __launch_bounds__(64) ec2_kernel(
    const int* __restrict__ idx, const float* __restrict__ e1,
    const float* __restrict__ w1, const float* __restrict__ b1,
    const float* __restrict__ w2, const float* __restrict__ b2,
    float* __restrict__ e2out)
{
  const int i = blockIdx.x, g = blockIdx.y;
  const int lane = threadIdx.x;
  __shared__ float gl[KNN*EO];
  __shared__ float hsh[EO];
  {
    const int k = lane >> 3, q = lane & 7;
    const int nb = idx[(g*NN+i)*8 + k];
    *(float4*)&gl[k*EO + q*4] = *(const float4*)(e1 + (g*NN+nb)*EO + q*4);
  }
  __syncthreads();
  const int e = lane & 31, hf = lane >> 5;
  float ak[8];
#pragma unroll
  for (int k = 0; k < 8; k++) ak[k] = 0.f;
  const int cbeg = hf*16;
  for (int c = cbeg; c < cbeg+16; c++) {
#pragma unroll
    for (int k = 0; k < 8; k++)
      ak[k] += gl[k*EO+c] * w1[(c*8+k)*EO + e];
  }
  float acc = ((ak[0]+ak[1])+(ak[2]+ak[3])) + ((ak[4]+ak[5])+(ak[6]+ak[7]));
  acc += __shfl_xor(acc, 32, 64);
  if (hf == 0) {
    float h = acc + b1[e];
    hsh[e] = fmaxf(h, 0.01f*h);
  }
  __syncthreads();
  if (lane < 32) {
    float o0=0.f, o1=0.f, o2=0.f, o3=0.f;
#pragma unroll
    for (int m = 0; m < 32; m += 4) {
      o0 += hsh[m+0] * w2[(m+0)*EO + lane];
      o1 += hsh[m+1] * w2[(m+1)*EO + lane];
      o2 += hsh[m+2] * w2[(m+2)*EO + lane];
      o3 += hsh[m+3] * w2[(m+3)*EO + lane];
    }
    float o = b2[lane] + ((o0+o1)+(o2+o3));
    o = fmaxf(o, 0.01f*o);
    e2out[(g*NN+i)*EO + lane] = o;
  }
}

__global__ void __launch_bounds__(256) stats_kernel(
    const float* __restrict__ feat0, const float* __restrict__ feat1,
    const float* __restrict__ e1, const float* __restrict__ e2,
    const float* __restrict__ bn_g,
    float* __restrict__ mu_out, float* __restrict__ sg_out)
{
  const int c = blockIdx.x;
  const int tid = threadIdx.x;
  double s1=0, s2=0, q1=0, q2=0;
  for (int t = tid; t < 2*NN; t += 256) {
    int g = t >= NN;
    int i = t - g*NN;
    float val;
    if (c < IN_F)      val = (g ? feat1 : feat0)[i*IN_F + c];
    else if (c < 100)  val = e1[(g*NN+i)*EO + (c-IN_F)];
    else               val = e2[(g*NN+i)*EO + (c-100)];
    double dv = val;
    double wf = (double)(NN-1-i), wsnd = (double)i;
    s1 += wf*dv;  s2 += wsnd*dv;
    double dq = dv*dv;
    q1 += wf*dq;  q2 += wsnd*dq;
  }
#pragma unroll
  for (int off = 32; off >= 1; off >>= 1) {
    s1 += __shfl_xor(s1, off, 64);
    s2 += __shfl_xor(s2, off, 64);
    q1 += __shfl_xor(q1, off, 64);
    q2 += __shfl_xor(q2, off, 64);
  }
  __shared__ double red[4][4];
  const int w = tid >> 6;
  if ((tid & 63) == 0) { red[w][0]=s1; red[w][1]=s2; red[w][2]=q1; red[w][3]=q2; }
  __syncthreads();
  if (tid == 0) {
    double t0 = red[0][0]+red[1][0]+red[2][0]+red[3][0];
    double t1 = red[0][1]+red[1][1]+red[2][1]+red[3][1];
    double t2 = red[0][2]+red[1][2]+red[2][2]+red[3][2];
    double t3 = red[0][3]+red[1][3]+red[2][3]+red[3][3];
    const double M2 = 2.0 * (double)NPAIR;
    double mu1 = t0/M2, mu2 = t1/M2;
    double v1 = t2/M2 - mu1*mu1;
    double v2 = t3/M2 - mu2*mu2;
    mu_out[c]           = (float)mu1;
    mu_out[HALF_FEAT+c] = (float)mu2;
    sg_out[c]           = (float)((double)bn_g[c] / sqrt(v1 + 1e-5));
    sg_out[HALF_FEAT+c] = (float)((double)bn_g[HALF_FEAT+c] / sqrt(v2 + 1e-5));
  }
}

__global__ void __launch_bounds__(64) uv_c0_kernel(
    const float* __restrict__ feat0, const float* __restrict__ feat1,
    const float* __restrict__ e1, const float* __restrict__ e2,
    const float* __restrict__ sg, const float* __restrict__ mu,
    const float* __restrict__ bn_b,
    const float* __restrict__ lin1_w, const float* __restrict__ lin1_b,
    float* __restrict__ u, float* __restrict__ v, float* __restrict__ c0g)
{
  const int i = blockIdx.x, g = blockIdx.y;
  const int t = threadIdx.x;
  if (i == NN) {
    if (g == 0 && t < EMB) {
      float a0=0.f, a1=0.f, a2=0.f, a3=0.f;
      for (int c = 0; c < FEAT; c += 4) {
        a0 += (bn_b[c+0] - mu[c+0]*sg[c+0]) * lin1_w[(c+0)*EMB + t];
        a1 += (bn_b[c+1] - mu[c+1]*sg[c+1]) * lin1_w[(c+1)*EMB + t];
        a2 += (bn_b[c+2] - mu[c+2]*sg[c+2]) * lin1_w[(c+2)*EMB + t];
        a3 += (bn_b[c+3] - mu[c+3]*sg[c+3]) * lin1_w[(c+3)*EMB + t];
      }
      c0g[t] = lin1_b[t] + ((a0+a1)+(a2+a3));
    }
    return;
  }
  __shared__ float x[HALF_FEAT];
  for (int c = t; c < IN_F; c += 64) x[c] = (g ? feat1 : feat0)[i*IN_F + c];
  if (t < 32) x[IN_F + t]     = e1[(g*NN+i)*EO + t];
  else        x[100 + (t-32)] = e2[(g*NN+i)*EO + (t-32)];
  __syncthreads();
  const int e = t & 31, hf = t >> 5;
  const int base = hf * HALF_FEAT;
  float a0=0.f, a1=0.f, a2=0.f, a3=0.f;
  for (int c = 0; c < HALF_FEAT; c += 4) {
    a0 += x[c+0] * sg[base+c+0] * lin1_w[(base+c+0)*EMB + e];
    a1 += x[c+1] * sg[base+c+1] * lin1_w[(base+c+1)*EMB + e];
    a2 += x[c+2] * sg[base+c+2] * lin1_w[(base+c+2)*EMB + e];
    a3 += x[c+3] * sg[base+c+3] * lin1_w[(base+c+3)*EMB + e];
  }
  float acc = ((a0+a1)+(a2+a3));
  float* dst = hf ? v : u;
  dst[(g*NN+i)*EMB + e] = acc;
}

// ---------------- Kernel E: pair MLP via split-bf16 MFMA (unchanged) ----------------
__global__ void __launch_bounds__(256) pair_kernel(
    const float* __restrict__ u, const float* __restrict__ v,
    const float* __restrict__ c0g,
    const float* __restrict__ lin2_w, const float* __restrict__ lin2_b,
    const float* __restrict__ lin3_w, const float* __restrict__ lin3_b,
    float2* __restrict__ out)
{
  const int g = blockIdx.y;
  int rem = blockIdx.x;        // 0..1175 triangular tile id
  int a = 0;
  while (rem >= 48 - a) { rem -= 48 - a; a++; }
  const int b = a + rem;

  __shared__ float su[16*36], sv[16*36];
  __shared__ float wbuf[4][16*36];
  const int tid = threadIdx.x;
  {
    int r = tid >> 5, c = tid & 31;
    su[r*36+c] = u[(g*NN + a*16 + r)*EMB + c];
    sv[r*36+c] = v[(g*NN + b*16 + r)*EMB + c];
    r += 8;
    su[r*36+c] = u[(g*NN + a*16 + r)*EMB + c];
    sv[r*36+c] = v[(g*NN + b*16 + r)*EMB + c];
  }
  __syncthreads();

  const int lane = tid & 63, w = tid >> 6;
  const int q = lane & 15, kg = lane >> 4;   // q: m/n index, kg: k-group

  union { int i[4]; bf16x8 v; } whi0, wlo0, whi1, wlo1;
#pragma unroll
  for (int d = 0; d < 4; d++) {
    float w0a = lin2_w[(kg*8+2*d)*32 + q],      float_w0b = 0.f;
    (void)float_w0b;
    float w0b = lin2_w[(kg*8+2*d+1)*32 + q];
    float w1a = lin2_w[(kg*8+2*d)*32 + 16 + q], w1b = lin2_w[(kg*8+2*d+1)*32 + 16 + q];
    whi0.i[d] = pack_chop2(w0a, w0b);
    wlo0.i[d] = pack_chop2(w0a - chop(w0a), w0b - chop(w0b));
    whi1.i[d] = pack_chop2(w1a, w1b);
    wlo1.i[d] = pack_chop2(w1a - chop(w1a), w1b - chop(w1b));
  }
  float svc[8];
#pragma unroll
  for (int jj = 0; jj < 8; jj++)
    svc[jj] = sv[q*36 + kg*8 + jj] + c0g[kg*8+jj];
  float2 w3v[8]; float b2v[8];
#pragma unroll
  for (int jj = 0; jj < 8; jj++) {
    w3v[jj] = ((const float2*)lin3_w)[kg*8+jj];
    b2v[jj] = lin2_b[kg*8+jj];
  }
  const float b30 = lin3_b[0], b31 = lin3_b[1];

  float* wb = wbuf[w];
#pragma unroll
  for (int t = 0; t < 4; t++) {
    const int ty = w*4 + t;
    const float4 sa = *(const float4*)&su[ty*36 + kg*8];
    const float4 sb = *(const float4*)&su[ty*36 + kg*8 + 4];
    float se[8] = {sa.x, sa.y, sa.z, sa.w, sb.x, sb.y, sb.z, sb.w};
    union { int i[4]; bf16x8 v; } ahi, alo;
#pragma unroll
    for (int d = 0; d < 4; d++) {
      float s0 = se[2*d]   + svc[2*d];
      float s1 = se[2*d+1] + svc[2*d+1];
      s0 = fmaxf(s0, 0.01f*s0);
      s1 = fmaxf(s1, 0.01f*s1);
      ahi.i[d] = pack_chop2(s0, s1);
      alo.i[d] = pack_chop2(s0 - chop(s0), s1 - chop(s1));
    }
    f32x4 acc0 = {0.f,0.f,0.f,0.f}, acc1 = {0.f,0.f,0.f,0.f};
    acc0 = __builtin_amdgcn_mfma_f32_16x16x32_bf16(ahi.v, whi0.v, acc0, 0,0,0);
    acc1 = __builtin_amdgcn_mfma_f32_16x16x32_bf16(ahi.v, whi1.v, acc1, 0,0,0);
    acc0 = __builtin_amdgcn_mfma_f32_16x16x32_bf16(ahi.v, wlo0.v, acc0, 0,0,0);
    acc1 = __builtin_amdgcn_mfma_f32_16x16x32_bf16(ahi.v, wlo1.v, acc1, 0,0,0);
    acc0 = __builtin_amdgcn_mfma_f32_16x16x32_bf16(alo.v, whi0.v, acc0, 0,0,0);
    acc1 = __builtin_amdgcn_mfma_f32_16x16x32_bf16(alo.v, whi1.v, acc1, 0,0,0);
#pragma unroll
    for (int r = 0; r < 4; r++) {
      wb[(kg*4+r)*36 + q]      = acc0[r];
      wb[(kg*4+r)*36 + 16 + q] = acc1[r];
    }
    float o0 = 0.f, o1 = 0.f;
#pragma unroll
    for (int jj = 0; jj < 8; jj++) {
      float h = wb[q*36 + kg*8 + jj] + b2v[jj];
      h = fmaxf(h, 0.01f*h);
      o0 += h * w3v[jj].x;
      o1 += h * w3v[jj].y;
    }
    o0 += __shfl_xor(o0, 16, 64); o0 += __shfl_xor(o0, 32, 64);
    o1 += __shfl_xor(o1, 16, 64); o1 += __shfl_xor(o1, 32, 64);
    const int i = a*16 + ty, j = b*16 + q;
    if (lane < 16 && j > i) {
      long p = (long)i*NN - (long)i*(i+1)/2 + (j - i - 1);
      out[(long)g*NPAIR + p] = make_float2(o0 + b30, o1 + b31);
    }
  }
}

extern "C" void kernel_launch(void* const* d_in, const int* in_sizes, int n_in,
                              void* d_out, int out_size, void* d_ws, size_t ws_size,
                              hipStream_t stream)
{
  const float* feat0  = (const float*)d_in[0];
  const float* feat1  = (const float*)d_in[1];
  const float* ec1_w1 = (const float*)d_in[2];
  const float* ec1_b1 = (const float*)d_in[3];
  const float* ec1_w2 = (const float*)d_in[4];
  const float* ec1_b2 = (const float*)d_in[5];
  const float* ec2_w1 = (const float*)d_in[6];
  const float* ec2_b1 = (const float*)d_in[7];
  const float* ec2_w2 = (const float*)d_in[8];
  const float* ec2_b2 = (const float*)d_in[9];
  const float* bn_g   = (const float*)d_in[10];
  const float* bn_b   = (const float*)d_in[11];
  const float* lin1_w = (const float*)d_in[12];
  const float* lin1_b = (const float*)d_in[13];
  const float* lin2_w = (const float*)d_in[14];
  const float* lin2_b = (const float*)d_in[15];
  const float* lin3_w = (const float*)d_in[16];
  const float* lin3_b = (const float*)d_in[17];

  char* ws = (char*)d_ws;
  int*   idx = (int*)  (ws + 0);
  float* e1  = (float*)(ws + 49152);
  float* e2  = (float*)(ws + 245760);
  float* u   = (float*)(ws + 442368);
  float* v   = (float*)(ws + 638976);
  float* mu  = (float*)(ws + 835584);
  float* sg  = (float*)(ws + 836640);
  float* c0g = (float*)(ws + 837696);

  void* kargs[] = {
    (void*)&feat0, (void*)&feat1,
    (void*)&ec1_w1, (void*)&ec1_b1, (void*)&ec1_w2, (void*)&ec1_b2,
    (void*)&ec2_w1, (void*)&ec2_b1, (void*)&ec2_w2, (void*)&ec2_b2,
    (void*)&bn_g, (void*)&bn_b, (void*)&lin1_w, (void*)&lin1_b,
    (void*)&idx, (void*)&e1, (void*)&e2,
    (void*)&mu, (void*)&sg, (void*)&u, (void*)&v, (void*)&c0g
  };
  hipError_t cerr = hipLaunchCooperativeKernel(
      (const void*)fused_abcd_kernel, dim3(NN+1, 2), dim3(64, 1, 1),
      kargs, 0, stream);
  if (cerr != hipSuccess) {
    // fallback: original 4-kernel chain
    topk_ec1_kernel<<<dim3(768,2), 64, 0, stream>>>(feat0, feat1, ec1_w1, ec1_b1,
                                                    ec1_w2, ec1_b2, idx, e1);
    ec2_kernel<<<dim3(768,2), 64, 0, stream>>>(idx, e1, ec2_w1, ec2_b1,
                                               ec2_w2, ec2_b2, e2);
    stats_kernel<<<dim3(132), 256, 0, stream>>>(feat0, feat1, e1, e2, bn_g, mu, sg);
    uv_c0_kernel<<<dim3(769,2), 64, 0, stream>>>(feat0, feat1, e1, e2, sg, mu, bn_b,
                                                 lin1_w, lin1_b, u, v, c0g);
  }
  pair_kernel<<<dim3(1176,2), 256, 0, stream>>>(u, v, c0g, lin2_w, lin2_b,
                                                lin3_w, lin3_b, (float2*)d_out);
}